// Round 7
// baseline (809.504 us; speedup 1.0000x reference)
//
#include <hip/hip_runtime.h>
#include <stdint.h>

// AttractorDynamics: sigma = iterate(tanh(drive + (sigma @ J^T)/tau), 10)
// B=16384, M=1024, A=512, tau=0.1, sigma0=0.
// R7: settle = 256 blocks (1/CU) x 1024 thr (16 waves, 4/SIMD). 64-row
// stripes halve J L2 traffic vs R6 (1.15 GB); 4 waves/SIMD double latency
// hiding. Per-thread state budgeted to ~110 VGPR < 128 cap. sigma f16 in
// 64KB XOR-swizzled LDS; drive exact f32 in regs; J f16 direct from L2.

#define B_DIM 16384
#define M_DIM 1024
#define A_DIM 512

typedef short bf16x8 __attribute__((ext_vector_type(8)));
typedef _Float16 f16x8 __attribute__((ext_vector_type(8)));
typedef float f32x4 __attribute__((ext_vector_type(4)));

__device__ __forceinline__ unsigned short f2bf(float f) {
  unsigned int u = __float_as_uint(f);
  unsigned int r = (u + 0x7FFFu + ((u >> 16) & 1u)) >> 16;  // RNE
  return (unsigned short)r;
}
__device__ __forceinline__ float bf2f(unsigned short s) {
  return __uint_as_float(((unsigned int)s) << 16);
}
__device__ __forceinline__ float fast_tanh(float x) {
  float t = __expf(2.0f * x);
  return fmaf(-2.0f, __builtin_amdgcn_rcpf(t + 1.0f), 1.0f);
}

// ---- prep: split fp32 -> bf16 hi + bf16 lo (for W) ----
__global__ void split_kernel(const float* __restrict__ src,
                             unsigned short* __restrict__ hi,
                             unsigned short* __restrict__ lo,
                             int n, float scale) {
  int i = blockIdx.x * 256 + threadIdx.x;
  if (i < n) {
    float v = src[i] * scale;
    unsigned short h = f2bf(v);
    hi[i] = h;
    lo[i] = f2bf(v - bf2f(h));
  }
}

// ---- prep: J/tau -> single f16 ----
__global__ void j16_kernel(const float* __restrict__ src,
                           _Float16* __restrict__ dst, int n, float scale) {
  int i = blockIdx.x * 256 + threadIdx.x;
  if (i < n) dst[i] = (_Float16)(src[i] * scale);
}

// ---- drive GEMM (R1 structure, unchanged): drive = x@W^T + b ----
__global__ __launch_bounds__(256) void drive_kernel(
    const float* __restrict__ x, const unsigned short* __restrict__ Whi,
    const unsigned short* __restrict__ Wlo, const float* __restrict__ bias,
    float* __restrict__ drive) {
  __shared__ __align__(16) unsigned short Ah[128][40];
  __shared__ __align__(16) unsigned short Al[128][40];
  __shared__ __align__(16) unsigned short Bh[128][40];
  __shared__ __align__(16) unsigned short Bl[128][40];

  const int t = threadIdx.x;
  const int bm = blockIdx.y, bn = blockIdx.x;
  const int row = t >> 1, half = t & 1;
  const int lane = t & 63, wave = t >> 6;
  const int wm = wave >> 1, wn = wave & 1;
  const int quad = lane >> 4, l16 = lane & 15;

  f32x4 acc[4][4] = {};

  const float* xp = x + (size_t)(bm * 128 + row) * M_DIM + half * 16;
  const unsigned short* wh = Whi + (size_t)(bn * 128 + row) * M_DIM + half * 16;
  const unsigned short* wl = Wlo + (size_t)(bn * 128 + row) * M_DIM + half * 16;

  for (int k0 = 0; k0 < M_DIM; k0 += 32) {
    float4 v[4];
#pragma unroll
    for (int q = 0; q < 4; ++q) v[q] = *(const float4*)(xp + k0 + 4 * q);
    unsigned short hiv[16], lov[16];
#pragma unroll
    for (int q = 0; q < 4; ++q) {
      float fv[4] = {v[q].x, v[q].y, v[q].z, v[q].w};
#pragma unroll
      for (int e = 0; e < 4; ++e) {
        unsigned short h = f2bf(fv[e]);
        hiv[4 * q + e] = h;
        lov[4 * q + e] = f2bf(fv[e] - bf2f(h));
      }
    }
    *(uint4*)&Ah[row][half * 16]     = *(uint4*)&hiv[0];
    *(uint4*)&Ah[row][half * 16 + 8] = *(uint4*)&hiv[8];
    *(uint4*)&Al[row][half * 16]     = *(uint4*)&lov[0];
    *(uint4*)&Al[row][half * 16 + 8] = *(uint4*)&lov[8];
    *(uint4*)&Bh[row][half * 16]     = *(const uint4*)(wh + k0);
    *(uint4*)&Bh[row][half * 16 + 8] = *(const uint4*)(wh + k0 + 8);
    *(uint4*)&Bl[row][half * 16]     = *(const uint4*)(wl + k0);
    *(uint4*)&Bl[row][half * 16 + 8] = *(const uint4*)(wl + k0 + 8);
    __syncthreads();

    bf16x8 ah[4], al[4], bh[4], bl[4];
#pragma unroll
    for (int i = 0; i < 4; ++i) {
      ah[i] = *(const bf16x8*)&Ah[wm * 64 + i * 16 + l16][quad * 8];
      al[i] = *(const bf16x8*)&Al[wm * 64 + i * 16 + l16][quad * 8];
    }
#pragma unroll
    for (int j = 0; j < 4; ++j) {
      bh[j] = *(const bf16x8*)&Bh[wn * 64 + j * 16 + l16][quad * 8];
      bl[j] = *(const bf16x8*)&Bl[wn * 64 + j * 16 + l16][quad * 8];
    }
#pragma unroll
    for (int i = 0; i < 4; ++i)
#pragma unroll
      for (int j = 0; j < 4; ++j) {
        acc[i][j] = __builtin_amdgcn_mfma_f32_16x16x32_bf16(ah[i], bh[j], acc[i][j], 0, 0, 0);
        acc[i][j] = __builtin_amdgcn_mfma_f32_16x16x32_bf16(ah[i], bl[j], acc[i][j], 0, 0, 0);
        acc[i][j] = __builtin_amdgcn_mfma_f32_16x16x32_bf16(al[i], bh[j], acc[i][j], 0, 0, 0);
      }
    __syncthreads();
  }

#pragma unroll
  for (int i = 0; i < 4; ++i)
#pragma unroll
    for (int j = 0; j < 4; ++j) {
      int gcol = bn * 128 + wn * 64 + j * 16 + l16;
      float bv = bias[gcol];
#pragma unroll
      for (int r = 0; r < 4; ++r) {
        int grow = bm * 128 + wm * 64 + i * 16 + quad * 4 + r;
        drive[(size_t)grow * A_DIM + gcol] = acc[i][j][r] + bv;
      }
    }
}

// ---- settle: 10 steps fused. 1024 thr (16 waves, 4/SIMD), 64-row stripe.
// wave w: m-half mh=w>>3 (rows mh*32+[0,32)), n-slice ns=w&7 (cols ns*64+[0,64)).
// sigma f16 in XOR-swizzled LDS: addr = row*512 + (((col>>3)^(row&7))<<3)+(col&7).
// drive exact f32 in 32 regs; J f16 direct from L2 (4 base ptrs, imm chunk offs).
__global__ __launch_bounds__(1024, 4) void settle_kernel(
    const float* __restrict__ drive, const _Float16* __restrict__ Jf,
    float* __restrict__ out) {
  __shared__ __align__(16) _Float16 sigL[64 * 512];  // 64 KB

  const int t = threadIdx.x;
  const int bm = blockIdx.x;              // rows [bm*64, +64)
  const int lane = t & 63, w = t >> 6;    // 16 waves
  const int mh = w >> 3, ns = w & 7;
  const int quad = lane >> 4, l16 = lane & 15;

  float drv[2][4][4];  // 32 f32, exact drive, lives all 10 steps
  f32x4 acc[2][4];

  // one-time drive load (coalesced 64B granules) + sigma1 = tanh -> LDS
#pragma unroll
  for (int i = 0; i < 2; ++i)
#pragma unroll
    for (int j = 0; j < 4; ++j) {
      const int col = ns * 64 + j * 16 + l16;
#pragma unroll
      for (int r = 0; r < 4; ++r) {
        const int row = mh * 32 + i * 16 + quad * 4 + r;
        float dv = drive[(size_t)(bm * 64 + row) * A_DIM + col];
        drv[i][j][r] = dv;
        sigL[row * 512 + (((col >> 3) ^ (row & 7)) << 3) + (col & 7)] =
            (_Float16)fast_tanh(dv);
      }
    }
  __syncthreads();

  // J base pointers per n-tile (constant across steps; chunk via imm offset)
  const _Float16* jp[4];
#pragma unroll
  for (int j = 0; j < 4; ++j)
    jp[j] = Jf + (size_t)(ns * 64 + j * 16 + l16) * A_DIM + quad * 8;

  for (int s = 0; s < 9; ++s) {
#pragma unroll
    for (int i = 0; i < 2; ++i)
#pragma unroll
      for (int j = 0; j < 4; ++j) acc[i][j] = (f32x4){0.f, 0.f, 0.f, 0.f};

#pragma unroll
    for (int c = 0; c < A_DIM / 32; ++c) {  // 16 k-chunks of 32
      f16x8 af[2];
#pragma unroll
      for (int i = 0; i < 2; ++i)
        af[i] = *(const f16x8*)&sigL[(mh * 32 + i * 16 + l16) * 512 +
                                     (((c * 4 + quad) ^ (l16 & 7)) << 3)];
      f16x8 bh[4];
#pragma unroll
      for (int j = 0; j < 4; ++j) bh[j] = *(const f16x8*)(jp[j] + c * 32);
#pragma unroll
      for (int j = 0; j < 4; ++j)
#pragma unroll
        for (int i = 0; i < 2; ++i)
          acc[i][j] = __builtin_amdgcn_mfma_f32_16x16x32_f16(af[i], bh[j], acc[i][j], 0, 0, 0);
    }

    if (s < 8) {
      __syncthreads();  // all waves done reading sigma_t
#pragma unroll
      for (int i = 0; i < 2; ++i)
#pragma unroll
        for (int j = 0; j < 4; ++j) {
          const int col = ns * 64 + j * 16 + l16;
#pragma unroll
          for (int r = 0; r < 4; ++r) {
            const int row = mh * 32 + i * 16 + quad * 4 + r;
            sigL[row * 512 + (((col >> 3) ^ (row & 7)) << 3) + (col & 7)] =
                (_Float16)fast_tanh(drv[i][j][r] + acc[i][j][r]);
          }
        }
      __syncthreads();
    } else {
#pragma unroll
      for (int i = 0; i < 2; ++i)
#pragma unroll
        for (int j = 0; j < 4; ++j) {
          const int col = ns * 64 + j * 16 + l16;
#pragma unroll
          for (int r = 0; r < 4; ++r) {
            const int row = bm * 64 + mh * 32 + i * 16 + quad * 4 + r;
            out[(size_t)row * A_DIM + col] =
                fast_tanh(drv[i][j][r] + acc[i][j][r]);
          }
        }
    }
  }
}

extern "C" void kernel_launch(void* const* d_in, const int* in_sizes, int n_in,
                              void* d_out, int out_size, void* d_ws, size_t ws_size,
                              hipStream_t stream) {
  const float* x = (const float*)d_in[0];
  const float* W = (const float*)d_in[1];
  const float* b = (const float*)d_in[2];
  const float* J = (const float*)d_in[3];
  float* out = (float*)d_out;

  char* ws = (char*)d_ws;
  float* drive        = (float*)(ws);                      // 33,554,432 B
  unsigned short* Whi = (unsigned short*)(ws + 33554432);  //  1,048,576 B
  unsigned short* Wlo = (unsigned short*)(ws + 34603008);  //  1,048,576 B
  _Float16* Jf        = (_Float16*)(ws + 35651584);        //    524,288 B

  const int nW = A_DIM * M_DIM;
  const int nJ = A_DIM * A_DIM;
  split_kernel<<<(nW + 255) / 256, 256, 0, stream>>>(W, Whi, Wlo, nW, 1.0f);
  j16_kernel<<<(nJ + 255) / 256, 256, 0, stream>>>(J, Jf, nJ, 10.0f);

  dim3 grid(A_DIM / 128, B_DIM / 128);  // (4, 128)
  drive_kernel<<<grid, 256, 0, stream>>>(x, Whi, Wlo, b, drive);

  settle_kernel<<<B_DIM / 64, 1024, 0, stream>>>(drive, Jf, out);
}